// Round 10
// baseline (274.374 us; speedup 1.0000x reference)
//
#include <hip/hip_runtime.h>

// Problem constants (fixed by the reference)
#define N_NODES 16384
#define N_EDGES 262144
#define E_TOT   (N_EDGES + N_NODES)   // edges + self loops = 278528
#define NEG_SLOPE 0.2f

typedef __attribute__((ext_vector_type(8))) short short8;
typedef __attribute__((ext_vector_type(4))) float floatx4;
typedef __attribute__((ext_vector_type(2))) float floatx2;
typedef __attribute__((ext_vector_type(4))) int intx4;

__device__ __forceinline__ float bf2f(ushort u) {
    return __uint_as_float(((unsigned)u) << 16);
}
__device__ __forceinline__ ushort f2bf(float f) {
    unsigned u = __float_as_uint(f);
    u += 0x7fffu + ((u >> 16) & 1u);   // round-to-nearest-even
    return (ushort)(u >> 16);
}
__device__ __forceinline__ float leaky(float x) {
    return x > 0.f ? x : NEG_SLOPE * x;
}

// async global->LDS, 16B per lane. LDS dest = wave-uniform base + lane*16.
__device__ __forceinline__ void load_lds16(const void* g, void* l) {
    __builtin_amdgcn_global_load_lds(
        (const __attribute__((address_space(1))) unsigned int*)g,
        (__attribute__((address_space(3))) unsigned int*)l, 16, 0, 0);
}

// ---------------------------------------------------------------------------
// Fused prep: x f32->bf16 cast, 3 weight transposes (+bf16), counts zeroing.
// ---------------------------------------------------------------------------
#define PREP_CAST   524288
#define PREP_T0     (PREP_CAST)
#define PREP_T1     (PREP_T0 + 65536)
#define PREP_T2     (PREP_T1 + 131072)
#define PREP_Z      (PREP_T2 + 262144)
#define PREP_TOT    (PREP_Z + 4096)

__global__ __launch_bounds__(256) void k_prep(const float* __restrict__ x,
                                              ushort* __restrict__ xb,
                                              const float* __restrict__ Wfc,
                                              ushort* __restrict__ WfcT,
                                              const float* __restrict__ W1,
                                              ushort* __restrict__ W1T,
                                              const float* __restrict__ W2,
                                              ushort* __restrict__ W2T,
                                              int* __restrict__ counts) {
    int idx = blockIdx.x * 256 + threadIdx.x;
    if (idx < PREP_CAST) {
        floatx4 v0 = *(const floatx4*)(x + (size_t)idx * 8);
        floatx4 v1 = *(const floatx4*)(x + (size_t)idx * 8 + 4);
        short8 r;
        r[0] = (short)f2bf(v0[0]); r[1] = (short)f2bf(v0[1]);
        r[2] = (short)f2bf(v0[2]); r[3] = (short)f2bf(v0[3]);
        r[4] = (short)f2bf(v1[0]); r[5] = (short)f2bf(v1[1]);
        r[6] = (short)f2bf(v1[2]); r[7] = (short)f2bf(v1[3]);
        *(short8*)(xb + (size_t)idx * 8) = r;
    } else if (idx < PREP_T1) {
        int t = idx - PREP_T0;                 // K=256, N=256
        int k = t >> 8, n = t & 255;
        WfcT[n * 256 + k] = f2bf(Wfc[t]);
    } else if (idx < PREP_T2) {
        int t = idx - PREP_T1;                 // K=256, N=512
        int k = t >> 9, n = t & 511;
        W1T[n * 256 + k] = f2bf(W1[t]);
    } else if (idx < PREP_Z) {
        int t = idx - PREP_T2;                 // K=512, N=512
        int k = t >> 9, n = t & 511;
        W2T[n * 512 + k] = f2bf(W2[t]);
    } else if (idx < PREP_TOT) {
        int t = idx - PREP_Z;
        *(intx4*)(counts + t * 4) = (intx4){0, 0, 0, 0};
    }
}

// ---------------------------------------------------------------------------
// CSR build: histogram of dst, shfl-based scan, scatter src indices
// ---------------------------------------------------------------------------
__global__ __launch_bounds__(256) void k_hist(const int* __restrict__ adj,
                                              int* __restrict__ counts) {
    int e = blockIdx.x * 256 + threadIdx.x;
    if (e < E_TOT) {
        int d = (e < N_EDGES) ? adj[N_EDGES + e] : (e - N_EDGES);
        atomicAdd(&counts[d], 1);
    }
}

__global__ __launch_bounds__(1024) void k_scan(const int* __restrict__ counts,
                                               int* __restrict__ offs,
                                               int* __restrict__ cursor) {
    __shared__ int wsum[16];
    int t = threadIdx.x, lane = t & 63, w = t >> 6;
    int local[16];
    int tot = 0;
#pragma unroll
    for (int i = 0; i < 16; i++) {
        local[i] = tot;
        tot += counts[t * 16 + i];
    }
    int incl = tot;   // wave-inclusive scan over thread totals
#pragma unroll
    for (int d = 1; d < 64; d <<= 1) {
        int v = __shfl_up(incl, d, 64);
        if (lane >= d) incl += v;
    }
    if (lane == 63) wsum[w] = incl;
    __syncthreads();
    if (w == 0) {
        int v = (lane < 16) ? wsum[lane] : 0;
#pragma unroll
        for (int d = 1; d < 16; d <<= 1) {
            int u = __shfl_up(v, d, 64);
            if (lane >= d) v += u;
        }
        if (lane < 16) wsum[lane] = v;
    }
    __syncthreads();
    int base = ((w == 0) ? 0 : wsum[w - 1]) + incl - tot;
#pragma unroll
    for (int i = 0; i < 16; i++) {
        int o = base + local[i];
        offs[t * 16 + i] = o;
        cursor[t * 16 + i] = o;
    }
    if (t == 1023) offs[N_NODES] = wsum[15];
}

__global__ __launch_bounds__(256) void k_scatter(const int* __restrict__ adj,
                                                 int* __restrict__ cursor,
                                                 int* __restrict__ esrc) {
    int e = blockIdx.x * 256 + threadIdx.x;
    if (e < E_TOT) {
        int s, d;
        if (e < N_EDGES) { s = adj[e]; d = adj[N_EDGES + e]; }
        else             { s = e - N_EDGES; d = s; }
        int pos = atomicAdd(&cursor[d], 1);
        esrc[pos] = s;
    }
}

// ---------------------------------------------------------------------------
// 128x128-tile GEMM, async staging (m97 structure): BK=64, 4 waves (2x2 of
// 64x64), 4x4 MFMA tiles/wave. global_load_lds width=16, unpadded LDS.
// mfma_f32_16x16x32_bf16 layouts (HW-verified):
//   A frag: A[m=lane&15][k=(lane>>4)*8 + j]
//   B frag: B[k=(lane>>4)*8 + j][n=lane&15]  (from BT rows)
//   C/D:    col=lane&15, row=(lane>>4)*4 + reg
// ---------------------------------------------------------------------------
#define GM 128
#define GN 128
#define GK 64

__global__ __launch_bounds__(256) void gemm128(const ushort* __restrict__ A,
                                               const ushort* __restrict__ BT,
                                               const float* __restrict__ bias,
                                               ushort* __restrict__ C,
                                               int M, int Nc, int K, int relu) {
    __shared__ ushort As[GM * GK];   // 16 KB
    __shared__ ushort Bs[GN * GK];   // 16 KB
    int tid = threadIdx.x, wave = tid >> 6, lane = tid & 63;
    int quad = lane >> 4, l16 = lane & 15;
    int bm = blockIdx.x * GM, bn = blockIdx.y * GN;
    int wm = (wave & 1) * 64, wn = (wave >> 1) * 64;

    floatx4 acc[4][4];
#pragma unroll
    for (int mi = 0; mi < 4; mi++)
#pragma unroll
        for (int ni = 0; ni < 4; ni++)
            acc[mi][ni] = (floatx4){0.f, 0.f, 0.f, 0.f};

    int lrow = lane >> 3;            // 0..7
    int lcol = (lane & 7) * 8;       // 0..56
    const ushort* pA = A + (size_t)(bm + wave * 32 + lrow) * K + lcol;
    const ushort* pB = BT + (size_t)(bn + wave * 32 + lrow) * K + lcol;
    ushort* lA = &As[(wave * 32) * GK];
    ushort* lB = &Bs[(wave * 32) * GK];

    for (int kb = 0; kb < K; kb += GK) {
#pragma unroll
        for (int t = 0; t < 4; t++) {
            load_lds16(pA + (size_t)(t * 8) * K + kb, lA + t * 8 * GK);
            load_lds16(pB + (size_t)(t * 8) * K + kb, lB + t * 8 * GK);
        }
        __syncthreads();

#pragma unroll
        for (int kk = 0; kk < GK; kk += 32) {
            short8 af[4], bf[4];
#pragma unroll
            for (int mi = 0; mi < 4; mi++)
                af[mi] = *(const short8*)&As[(wm + mi * 16 + l16) * GK + kk + quad * 8];
#pragma unroll
            for (int ni = 0; ni < 4; ni++)
                bf[ni] = *(const short8*)&Bs[(wn + ni * 16 + l16) * GK + kk + quad * 8];
#pragma unroll
            for (int mi = 0; mi < 4; mi++)
#pragma unroll
                for (int ni = 0; ni < 4; ni++)
                    acc[mi][ni] = __builtin_amdgcn_mfma_f32_16x16x32_bf16(
                        af[mi], bf[ni], acc[mi][ni], 0, 0, 0);
        }
        __syncthreads();
    }

#pragma unroll
    for (int mi = 0; mi < 4; mi++) {
        int row = bm + wm + mi * 16 + quad * 4;
#pragma unroll
        for (int ni = 0; ni < 4; ni++) {
            int col = bn + wn + ni * 16 + l16;
            float bv = bias ? bias[col] : 0.f;
#pragma unroll
            for (int i = 0; i < 4; i++) {
                float v = acc[mi][ni][i] + bv;
                if (relu) v = fmaxf(v, 0.f);
                C[(size_t)(row + i) * Nc + col] = f2bf(v);
            }
        }
    }
}

// ---------------------------------------------------------------------------
// Attention logits: h bf16, a-vectors fp32. One wave per node.
// ---------------------------------------------------------------------------
__global__ __launch_bounds__(256) void k_dots(const ushort* __restrict__ h,
                                              const float* __restrict__ asrc,
                                              const float* __restrict__ adst,
                                              float* __restrict__ als,
                                              float* __restrict__ ald,
                                              int heads) {
    int wave = threadIdx.x >> 6, lane = threadIdx.x & 63;
    int n = blockIdx.x * 4 + wave;
    const ushort* hr = h + (size_t)n * 512;
    int c = lane * 8;
    short8 hv = *(const short8*)(hr + c);
    floatx4 s0 = *(const floatx4*)(asrc + c);
    floatx4 s1 = *(const floatx4*)(asrc + c + 4);
    floatx4 d0 = *(const floatx4*)(adst + c);
    floatx4 d1 = *(const floatx4*)(adst + c + 4);
    float ps = 0.f, pd = 0.f;
#pragma unroll
    for (int j = 0; j < 4; j++) {
        float hf0 = bf2f((ushort)hv[j]);
        float hf1 = bf2f((ushort)hv[j + 4]);
        ps += hf0 * s0[j] + hf1 * s1[j];
        pd += hf0 * d0[j] + hf1 * d1[j];
    }
    int w = (heads == 2) ? 32 : 64;
    for (int m = 1; m < w; m <<= 1) {
        ps += __shfl_xor(ps, m, 64);
        pd += __shfl_xor(pd, m, 64);
    }
    if (heads == 2) {
        if (lane == 0)  { als[n * 2]     = ps; ald[n * 2]     = pd; }
        if (lane == 32) { als[n * 2 + 1] = ps; ald[n * 2 + 1] = pd; }
    } else {
        if (lane == 0)  { als[n] = ps; ald[n] = pd; }
    }
}

// ---------------------------------------------------------------------------
// Segment softmax + aggregation, ONE wave per node (R10: parity split of R9
// reverted — it was neutral w/ extra conflicts). Gather unrolled x8: 8
// independent 16B row-loads in flight per wave. float2 packed accumulation
// (v_pk_fma_f32). All shfl broadcasts unconditional (R8 lesson).
// ---------------------------------------------------------------------------
__global__ __launch_bounds__(256) void k_agg(const ushort* __restrict__ h,
                                             const float* __restrict__ als,
                                             const float* __restrict__ ald,
                                             const int* __restrict__ offs,
                                             const int* __restrict__ esrc,
                                             const float* __restrict__ bias,
                                             ushort* __restrict__ outb,
                                             float* __restrict__ outf,
                                             int heads) {
    int wave = threadIdx.x >> 6, lane = threadIdx.x & 63;
    int n = blockIdx.x * 4 + wave;
    int base = offs[n];
    int deg  = offs[n + 1] - base;

    int myhead = (heads == 2) ? (lane >> 5) : 0;
    int c = (heads == 2) ? (myhead * 256 + (lane & 31) * 8) : lane * 8;

    float aldh0 = ald[n * heads];
    float aldh1 = (heads == 2) ? ald[n * heads + 1] : 0.f;

    // pass 1: per-head max
    float m0 = -1e30f, m1 = -1e30f;
    for (int cb = 0; cb < deg; cb += 64) {
        int i = cb + lane;
        if (i < deg) {
            int s = esrc[base + i];
            m0 = fmaxf(m0, leaky(als[s * heads] + aldh0));
            if (heads == 2) m1 = fmaxf(m1, leaky(als[s * 2 + 1] + aldh1));
        }
    }
#pragma unroll
    for (int msk = 1; msk < 64; msk <<= 1) {
        m0 = fmaxf(m0, __shfl_xor(m0, msk, 64));
        m1 = fmaxf(m1, __shfl_xor(m1, msk, 64));
    }

    // pass 2: per-head denom
    float s0 = 0.f, s1 = 0.f;
    for (int cb = 0; cb < deg; cb += 64) {
        int i = cb + lane;
        if (i < deg) {
            int s = esrc[base + i];
            s0 += __expf(leaky(als[s * heads] + aldh0) - m0);
            if (heads == 2) s1 += __expf(leaky(als[s * 2 + 1] + aldh1) - m1);
        }
    }
#pragma unroll
    for (int msk = 1; msk < 64; msk <<= 1) {
        s0 += __shfl_xor(s0, msk, 64);
        s1 += __shfl_xor(s1, msk, 64);
    }
    float inv0 = 1.f / (s0 + 1e-16f);
    float inv1 = 1.f / (s1 + 1e-16f);

    // pass 3: weighted gather-accumulate, 8 channels (16B) per lane per edge
    floatx2 acc2[4];
#pragma unroll
    for (int q = 0; q < 4; q++) acc2[q] = (floatx2){0.f, 0.f};
    const ushort* hc = h + c;

    for (int cb = 0; cb < deg; cb += 64) {
        int i = cb + lane;
        int sv = 0;
        float p0 = 0.f, p1 = 0.f;
        if (i < deg) {
            sv = esrc[base + i];
            p0 = __expf(leaky(als[sv * heads] + aldh0) - m0) * inv0;
            if (heads == 2) p1 = __expf(leaky(als[sv * 2 + 1] + aldh1) - m1) * inv1;
        }
        int cnt = min(64, deg - cb);
        int j = 0;
        for (; j + 8 <= cnt; j += 8) {
            int sj[8];
            float alv[8];
            const uint* rp[8];
#pragma unroll
            for (int u = 0; u < 8; u++) {
                sj[u] = __shfl(sv, j + u, 64);
                float a0 = __shfl(p0, j + u, 64);
                float a1 = __shfl(p1, j + u, 64);
                alv[u] = myhead ? a1 : a0;
                rp[u] = (const uint*)(hc + (size_t)sj[u] * 512);
            }
            uint4 rv[8];
#pragma unroll
            for (int u = 0; u < 8; u++) rv[u] = *(const uint4*)rp[u];
#pragma unroll
            for (int u = 0; u < 8; u++) {
                floatx2 al2 = (floatx2){alv[u], alv[u]};
                uint w0 = rv[u].x, w1 = rv[u].y, w2 = rv[u].z, w3 = rv[u].w;
                floatx2 f0 = (floatx2){bf2f((ushort)(w0 & 0xffffu)), bf2f((ushort)(w0 >> 16))};
                floatx2 f1 = (floatx2){bf2f((ushort)(w1 & 0xffffu)), bf2f((ushort)(w1 >> 16))};
                floatx2 f2 = (floatx2){bf2f((ushort)(w2 & 0xffffu)), bf2f((ushort)(w2 >> 16))};
                floatx2 f3 = (floatx2){bf2f((ushort)(w3 & 0xffffu)), bf2f((ushort)(w3 >> 16))};
                acc2[0] += al2 * f0;
                acc2[1] += al2 * f1;
                acc2[2] += al2 * f2;
                acc2[3] += al2 * f3;
            }
        }
        for (; j < cnt; j++) {
            int s = __shfl(sv, j, 64);
            float a0 = __shfl(p0, j, 64), a1 = __shfl(p1, j, 64);
            float al = myhead ? a1 : a0;
            floatx2 al2 = (floatx2){al, al};
            uint4 rv = *(const uint4*)(hc + (size_t)s * 512);
            floatx2 f0 = (floatx2){bf2f((ushort)(rv.x & 0xffffu)), bf2f((ushort)(rv.x >> 16))};
            floatx2 f1 = (floatx2){bf2f((ushort)(rv.y & 0xffffu)), bf2f((ushort)(rv.y >> 16))};
            floatx2 f2 = (floatx2){bf2f((ushort)(rv.z & 0xffffu)), bf2f((ushort)(rv.z >> 16))};
            floatx2 f3 = (floatx2){bf2f((ushort)(rv.w & 0xffffu)), bf2f((ushort)(rv.w >> 16))};
            acc2[0] += al2 * f0;
            acc2[1] += al2 * f1;
            acc2[2] += al2 * f2;
            acc2[3] += al2 * f3;
        }
    }

    float v[8];
#pragma unroll
    for (int q = 0; q < 4; q++) {
        v[2 * q]     = fmaxf(acc2[q][0] + bias[c + 2 * q], 0.f);
        v[2 * q + 1] = fmaxf(acc2[q][1] + bias[c + 2 * q + 1], 0.f);
    }
    if (outf) {
        float* op = outf + (size_t)n * 512 + c;
        *(floatx4*)op       = (floatx4){v[0], v[1], v[2], v[3]};
        *(floatx4*)(op + 4) = (floatx4){v[4], v[5], v[6], v[7]};
    } else {
        short8 r;
#pragma unroll
        for (int q = 0; q < 8; q++) r[q] = (short)f2bf(v[q]);
        *(short8*)(outb + (size_t)n * 512 + c) = r;
    }
}

// ---------------------------------------------------------------------------
// R10: k_agg reverted to wave-per-node, gather unroll x8 + packed fp32 math.
// gemm128 async staging kept. Workspace ~52 MiB.
// ---------------------------------------------------------------------------
extern "C" void kernel_launch(void* const* d_in, const int* in_sizes, int n_in,
                              void* d_out, int out_size, void* d_ws, size_t ws_size,
                              hipStream_t stream) {
    const float* x   = (const float*)d_in[0];
    const int*   adj = (const int*)d_in[1];
    const float* Wfc = (const float*)d_in[2];
    const float* bfc = (const float*)d_in[3];
    const float* W1  = (const float*)d_in[4];
    const float* a1s = (const float*)d_in[5];
    const float* a1d = (const float*)d_in[6];
    const float* b1  = (const float*)d_in[7];
    const float* W2  = (const float*)d_in[8];
    const float* a2s = (const float*)d_in[9];
    const float* a2d = (const float*)d_in[10];
    const float* b2  = (const float*)d_in[11];
    float* out = (float*)d_out;

    char* ws = (char*)d_ws;
    size_t off = 0;
    auto alloc = [&](size_t bytes) -> void* {
        void* p = ws + off;
        off += (bytes + 255) & ~(size_t)255;
        return p;
    };
    ushort* xb   = (ushort*)alloc((size_t)N_NODES * 256 * 2);
    ushort* h0b  = (ushort*)alloc((size_t)N_NODES * 256 * 2);
    ushort* h1b  = (ushort*)alloc((size_t)N_NODES * 512 * 2);
    ushort* g1b  = (ushort*)alloc((size_t)N_NODES * 512 * 2);
    int* counts  = (int*)alloc(N_NODES * 4);
    int* offs    = (int*)alloc((N_NODES + 1) * 4);
    int* cursor  = (int*)alloc(N_NODES * 4);
    int* esrc    = (int*)alloc(E_TOT * 4);
    ushort* WfcT = (ushort*)alloc(256 * 256 * 2);
    ushort* W1T  = (ushort*)alloc(512 * 256 * 2);
    ushort* W2T  = (ushort*)alloc(512 * 512 * 2);
    float* als1  = (float*)alloc(N_NODES * 2 * 4);
    float* ald1  = (float*)alloc(N_NODES * 2 * 4);
    float* als2  = (float*)alloc(N_NODES * 4);
    float* ald2  = (float*)alloc(N_NODES * 4);

    // fused prep: cast x, transpose 3 weights, zero counts
    k_prep<<<PREP_TOT / 256, 256, 0, stream>>>(x, xb, Wfc, WfcT, W1, W1T, W2, W2T,
                                               counts);

    // CSR build
    k_hist<<<(E_TOT + 255) / 256, 256, 0, stream>>>(adj, counts);
    k_scan<<<1, 1024, 0, stream>>>(counts, offs, cursor);
    k_scatter<<<(E_TOT + 255) / 256, 256, 0, stream>>>(adj, cursor, esrc);

    // h0 = relu(x @ Wfc + bfc)            [N,256] bf16
    gemm128<<<dim3(N_NODES / GM, 256 / GN), 256, 0, stream>>>(xb, WfcT, bfc, h0b,
                                                              N_NODES, 256, 256, 1);
    // h1 = h0 @ W1                        [N,512] bf16
    gemm128<<<dim3(N_NODES / GM, 512 / GN), 256, 0, stream>>>(h0b, W1T, nullptr, h1b,
                                                              N_NODES, 512, 256, 0);
    // gat1 attention + aggregation -> relu -> g1b (bf16)
    k_dots<<<N_NODES / 4, 256, 0, stream>>>(h1b, a1s, a1d, als1, ald1, 2);
    k_agg<<<N_NODES / 4, 256, 0, stream>>>(h1b, als1, ald1, offs, esrc, b1,
                                           g1b, nullptr, 2);

    // h2 = g1 @ W2                        [N,512] bf16 (h1b reused; h1 dead)
    gemm128<<<dim3(N_NODES / GM, 512 / GN), 256, 0, stream>>>(g1b, W2T, nullptr, h1b,
                                                              N_NODES, 512, 512, 0);
    // gat2 attention + aggregation -> relu -> out (fp32)
    k_dots<<<N_NODES / 4, 256, 0, stream>>>(h1b, a2s, a2d, als2, ald2, 1);
    k_agg<<<N_NODES / 4, 256, 0, stream>>>(h1b, als2, ald2, offs, esrc, b2,
                                           nullptr, out, 1);
}

// Round 11
// 274.147 us; speedup vs baseline: 1.0008x; 1.0008x over previous
//
#include <hip/hip_runtime.h>

// Problem constants (fixed by the reference)
#define N_NODES 16384
#define N_EDGES 262144
#define E_TOT   (N_EDGES + N_NODES)   // edges + self loops = 278528
#define NEG_SLOPE 0.2f

typedef __attribute__((ext_vector_type(8))) short short8;
typedef __attribute__((ext_vector_type(4))) float floatx4;
typedef __attribute__((ext_vector_type(4))) int intx4;

__device__ __forceinline__ float bf2f(ushort u) {
    return __uint_as_float(((unsigned)u) << 16);
}
__device__ __forceinline__ ushort f2bf(float f) {
    unsigned u = __float_as_uint(f);
    u += 0x7fffu + ((u >> 16) & 1u);   // round-to-nearest-even
    return (ushort)(u >> 16);
}
__device__ __forceinline__ float leaky(float x) {
    return x > 0.f ? x : NEG_SLOPE * x;
}

// ---------------------------------------------------------------------------
// Fused prep: x cast, 3 weight transposes, dst histogram (counts pre-zeroed
// by hipMemsetAsync before this dispatch).
// ---------------------------------------------------------------------------
#define PREP_CAST   524288
#define PREP_T0     (PREP_CAST)
#define PREP_T1     (PREP_T0 + 65536)
#define PREP_T2     (PREP_T1 + 131072)
#define PREP_H      (PREP_T2 + 262144)
#define PREP_TOT    (PREP_H + E_TOT)

__global__ __launch_bounds__(256) void k_prep(const float* __restrict__ x,
                                              ushort* __restrict__ xb,
                                              const float* __restrict__ Wfc,
                                              ushort* __restrict__ WfcT,
                                              const float* __restrict__ W1,
                                              ushort* __restrict__ W1T,
                                              const float* __restrict__ W2,
                                              ushort* __restrict__ W2T,
                                              const int* __restrict__ adj,
                                              int* __restrict__ counts) {
    int idx = blockIdx.x * 256 + threadIdx.x;
    if (idx < PREP_CAST) {
        floatx4 v0 = *(const floatx4*)(x + (size_t)idx * 8);
        floatx4 v1 = *(const floatx4*)(x + (size_t)idx * 8 + 4);
        short8 r;
        r[0] = (short)f2bf(v0[0]); r[1] = (short)f2bf(v0[1]);
        r[2] = (short)f2bf(v0[2]); r[3] = (short)f2bf(v0[3]);
        r[4] = (short)f2bf(v1[0]); r[5] = (short)f2bf(v1[1]);
        r[6] = (short)f2bf(v1[2]); r[7] = (short)f2bf(v1[3]);
        *(short8*)(xb + (size_t)idx * 8) = r;
    } else if (idx < PREP_T1) {
        int t = idx - PREP_T0;                 // K=256, N=256
        int k = t >> 8, n = t & 255;
        WfcT[n * 256 + k] = f2bf(Wfc[t]);
    } else if (idx < PREP_T2) {
        int t = idx - PREP_T1;                 // K=256, N=512
        int k = t >> 9, n = t & 511;
        W1T[n * 256 + k] = f2bf(W1[t]);
    } else if (idx < PREP_H) {
        int t = idx - PREP_T2;                 // K=512, N=512
        int k = t >> 9, n = t & 511;
        W2T[n * 512 + k] = f2bf(W2[t]);
    } else if (idx < PREP_TOT) {
        int e = idx - PREP_H;                  // dst histogram
        int d = (e < N_EDGES) ? adj[N_EDGES + e] : (e - N_EDGES);
        atomicAdd(&counts[d], 1);
    }
}

// ---------------------------------------------------------------------------
// CSR build: shfl-based scan, scatter src indices, per-segment src sort
// ---------------------------------------------------------------------------
__global__ __launch_bounds__(1024) void k_scan(const int* __restrict__ counts,
                                               int* __restrict__ offs,
                                               int* __restrict__ cursor) {
    __shared__ int wsum[16];
    int t = threadIdx.x, lane = t & 63, w = t >> 6;
    int local[16];
    int tot = 0;
#pragma unroll
    for (int i = 0; i < 16; i++) {
        local[i] = tot;
        tot += counts[t * 16 + i];
    }
    int incl = tot;   // wave-inclusive scan over thread totals
#pragma unroll
    for (int d = 1; d < 64; d <<= 1) {
        int v = __shfl_up(incl, d, 64);
        if (lane >= d) incl += v;
    }
    if (lane == 63) wsum[w] = incl;
    __syncthreads();
    if (w == 0) {
        int v = (lane < 16) ? wsum[lane] : 0;
#pragma unroll
        for (int d = 1; d < 16; d <<= 1) {
            int u = __shfl_up(v, d, 64);
            if (lane >= d) v += u;
        }
        if (lane < 16) wsum[lane] = v;
    }
    __syncthreads();
    int base = ((w == 0) ? 0 : wsum[w - 1]) + incl - tot;
#pragma unroll
    for (int i = 0; i < 16; i++) {
        int o = base + local[i];
        offs[t * 16 + i] = o;
        cursor[t * 16 + i] = o;
    }
    if (t == 1023) offs[N_NODES] = wsum[15];
}

__global__ __launch_bounds__(256) void k_scatter(const int* __restrict__ adj,
                                                 int* __restrict__ cursor,
                                                 int* __restrict__ esrc) {
    int e = blockIdx.x * 256 + threadIdx.x;
    if (e < E_TOT) {
        int s, d;
        if (e < N_EDGES) { s = adj[e]; d = adj[N_EDGES + e]; }
        else             { s = e - N_EDGES; d = s; }
        int pos = atomicAdd(&cursor[d], 1);
        esrc[pos] = s;
    }
}

// Sort each node's CSR segment by src (wave-per-node rank sort, deg<=64).
// Ascending src order aligns concurrent waves' gathers into a moving address
// window -> L2-resident working set in k_agg. Order is math-neutral.
__global__ __launch_bounds__(256) void k_sort(const int* __restrict__ offs,
                                              int* __restrict__ esrc) {
    int wave = threadIdx.x >> 6, lane = threadIdx.x & 63;
    int n = blockIdx.x * 4 + wave;
    int base = offs[n];
    int deg  = offs[n + 1] - base;
    if (deg > 64) return;   // astronomically unlikely; leave unsorted (correct)
    int v = (lane < deg) ? esrc[base + lane] : 0x7fffffff;
    int rank = 0;
#pragma unroll
    for (int j = 0; j < 64; j++) {
        int vj = __shfl(v, j, 64);
        rank += (vj < v) || (vj == v && j < lane);
    }
    if (lane < deg) esrc[base + rank] = v;
}

// ---------------------------------------------------------------------------
// 128x128-tile GEMM (R8-proven): BK=64, 4 waves (2x2 of 64x64), 4x4 MFMA
// tiles/wave. Staging: short8 global loads -> ds_write_b128, padded LDS.
// mfma_f32_16x16x32_bf16 layouts (HW-verified):
//   A frag: A[m=lane&15][k=(lane>>4)*8 + j]
//   B frag: B[k=(lane>>4)*8 + j][n=lane&15]  (from BT rows)
//   C/D:    col=lane&15, row=(lane>>4)*4 + reg
// ---------------------------------------------------------------------------
#define GM 128
#define GN 128
#define GK 64
#define LDK2 72

__global__ __launch_bounds__(256) void gemm128(const ushort* __restrict__ A,
                                               const ushort* __restrict__ BT,
                                               const float* __restrict__ bias,
                                               ushort* __restrict__ C,
                                               int M, int Nc, int K, int relu) {
    __shared__ ushort As[GM * LDK2];   // 18 KB
    __shared__ ushort Bs[GN * LDK2];   // 18 KB
    int tid = threadIdx.x, wave = tid >> 6, lane = tid & 63;
    int quad = lane >> 4, l16 = lane & 15;
    int bm = blockIdx.x * GM, bn = blockIdx.y * GN;
    int wm = (wave & 1) * 64, wn = (wave >> 1) * 64;

    floatx4 acc[4][4];
#pragma unroll
    for (int mi = 0; mi < 4; mi++)
#pragma unroll
        for (int ni = 0; ni < 4; ni++)
            acc[mi][ni] = (floatx4){0.f, 0.f, 0.f, 0.f};

    for (int kb = 0; kb < K; kb += GK) {
        short8 av[4], bv[4];
#pragma unroll
        for (int t = 0; t < 4; t++) {
            int ci = tid + 256 * t;
            int row = ci >> 3, col = (ci & 7) * 8;
            av[t] = *(const short8*)(A + (size_t)(bm + row) * K + kb + col);
            bv[t] = *(const short8*)(BT + (size_t)(bn + row) * K + kb + col);
        }
        __syncthreads();
#pragma unroll
        for (int t = 0; t < 4; t++) {
            int ci = tid + 256 * t;
            int row = ci >> 3, col = (ci & 7) * 8;
            *(short8*)&As[row * LDK2 + col] = av[t];
            *(short8*)&Bs[row * LDK2 + col] = bv[t];
        }
        __syncthreads();

#pragma unroll
        for (int kk = 0; kk < GK; kk += 32) {
            short8 af[4], bf[4];
#pragma unroll
            for (int mi = 0; mi < 4; mi++)
                af[mi] = *(const short8*)&As[(wm + mi * 16 + l16) * LDK2 + kk + quad * 8];
#pragma unroll
            for (int ni = 0; ni < 4; ni++)
                bf[ni] = *(const short8*)&Bs[(wn + ni * 16 + l16) * LDK2 + kk + quad * 8];
#pragma unroll
            for (int mi = 0; mi < 4; mi++)
#pragma unroll
                for (int ni = 0; ni < 4; ni++)
                    acc[mi][ni] = __builtin_amdgcn_mfma_f32_16x16x32_bf16(
                        af[mi], bf[ni], acc[mi][ni], 0, 0, 0);
        }
    }

#pragma unroll
    for (int mi = 0; mi < 4; mi++) {
        int row = bm + wm + mi * 16 + quad * 4;
#pragma unroll
        for (int ni = 0; ni < 4; ni++) {
            int col = bn + wn + ni * 16 + l16;
            float bv = bias ? bias[col] : 0.f;
#pragma unroll
            for (int i = 0; i < 4; i++) {
                float v = acc[mi][ni][i] + bv;
                if (relu) v = fmaxf(v, 0.f);
                C[(size_t)(row + i) * Nc + col] = f2bf(v);
            }
        }
    }
}

// ---------------------------------------------------------------------------
// Attention logits: h bf16, a-vectors fp32. One wave per node.
// ---------------------------------------------------------------------------
__global__ __launch_bounds__(256) void k_dots(const ushort* __restrict__ h,
                                              const float* __restrict__ asrc,
                                              const float* __restrict__ adst,
                                              float* __restrict__ als,
                                              float* __restrict__ ald,
                                              int heads) {
    int wave = threadIdx.x >> 6, lane = threadIdx.x & 63;
    int n = blockIdx.x * 4 + wave;
    const ushort* hr = h + (size_t)n * 512;
    int c = lane * 8;
    short8 hv = *(const short8*)(hr + c);
    floatx4 s0 = *(const floatx4*)(asrc + c);
    floatx4 s1 = *(const floatx4*)(asrc + c + 4);
    floatx4 d0 = *(const floatx4*)(adst + c);
    floatx4 d1 = *(const floatx4*)(adst + c + 4);
    float ps = 0.f, pd = 0.f;
#pragma unroll
    for (int j = 0; j < 4; j++) {
        float hf0 = bf2f((ushort)hv[j]);
        float hf1 = bf2f((ushort)hv[j + 4]);
        ps += hf0 * s0[j] + hf1 * s1[j];
        pd += hf0 * d0[j] + hf1 * d1[j];
    }
    int w = (heads == 2) ? 32 : 64;
    for (int m = 1; m < w; m <<= 1) {
        ps += __shfl_xor(ps, m, 64);
        pd += __shfl_xor(pd, m, 64);
    }
    if (heads == 2) {
        if (lane == 0)  { als[n * 2]     = ps; ald[n * 2]     = pd; }
        if (lane == 32) { als[n * 2 + 1] = ps; ald[n * 2 + 1] = pd; }
    } else {
        if (lane == 0)  { als[n] = ps; ald[n] = pd; }
    }
}

// ---------------------------------------------------------------------------
// Segment softmax + aggregation, one wave per node (R8-proven x4 unroll).
// All shfl broadcasts unconditional (R8 lesson: never shfl under
// myhead-divergent control flow).
// ---------------------------------------------------------------------------
__global__ __launch_bounds__(256) void k_agg(const ushort* __restrict__ h,
                                             const float* __restrict__ als,
                                             const float* __restrict__ ald,
                                             const int* __restrict__ offs,
                                             const int* __restrict__ esrc,
                                             const float* __restrict__ bias,
                                             ushort* __restrict__ outb,
                                             float* __restrict__ outf,
                                             int heads) {
    int wave = threadIdx.x >> 6, lane = threadIdx.x & 63;
    int n = blockIdx.x * 4 + wave;
    int base = offs[n];
    int deg  = offs[n + 1] - base;

    int myhead = (heads == 2) ? (lane >> 5) : 0;
    int c = (heads == 2) ? (myhead * 256 + (lane & 31) * 8) : lane * 8;

    float aldh0 = ald[n * heads];
    float aldh1 = (heads == 2) ? ald[n * heads + 1] : 0.f;

    // pass 1: per-head max
    float m0 = -1e30f, m1 = -1e30f;
    for (int cb = 0; cb < deg; cb += 64) {
        int i = cb + lane;
        if (i < deg) {
            int s = esrc[base + i];
            m0 = fmaxf(m0, leaky(als[s * heads] + aldh0));
            if (heads == 2) m1 = fmaxf(m1, leaky(als[s * 2 + 1] + aldh1));
        }
    }
#pragma unroll
    for (int msk = 1; msk < 64; msk <<= 1) {
        m0 = fmaxf(m0, __shfl_xor(m0, msk, 64));
        m1 = fmaxf(m1, __shfl_xor(m1, msk, 64));
    }

    // pass 2: per-head denom
    float s0 = 0.f, s1 = 0.f;
    for (int cb = 0; cb < deg; cb += 64) {
        int i = cb + lane;
        if (i < deg) {
            int s = esrc[base + i];
            s0 += __expf(leaky(als[s * heads] + aldh0) - m0);
            if (heads == 2) s1 += __expf(leaky(als[s * 2 + 1] + aldh1) - m1);
        }
    }
#pragma unroll
    for (int msk = 1; msk < 64; msk <<= 1) {
        s0 += __shfl_xor(s0, msk, 64);
        s1 += __shfl_xor(s1, msk, 64);
    }
    float inv0 = 1.f / (s0 + 1e-16f);
    float inv1 = 1.f / (s1 + 1e-16f);

    // pass 3: weighted gather-accumulate, 8 channels (16B) per lane per edge
    float acc[8];
#pragma unroll
    for (int q = 0; q < 8; q++) acc[q] = 0.f;
    const ushort* hc = h + c;

    for (int cb = 0; cb < deg; cb += 64) {
        int i = cb + lane;
        int sv = 0;
        float p0 = 0.f, p1 = 0.f;
        if (i < deg) {
            sv = esrc[base + i];
            p0 = __expf(leaky(als[sv * heads] + aldh0) - m0) * inv0;
            if (heads == 2) p1 = __expf(leaky(als[sv * 2 + 1] + aldh1) - m1) * inv1;
        }
        int cnt = min(64, deg - cb);
        int j = 0;
        for (; j + 4 <= cnt; j += 4) {
            int sj0 = __shfl(sv, j, 64);
            int sj1 = __shfl(sv, j + 1, 64);
            int sj2 = __shfl(sv, j + 2, 64);
            int sj3 = __shfl(sv, j + 3, 64);
            float a00 = __shfl(p0, j, 64),     a01 = __shfl(p1, j, 64);
            float a10 = __shfl(p0, j + 1, 64), a11 = __shfl(p1, j + 1, 64);
            float a20 = __shfl(p0, j + 2, 64), a21 = __shfl(p1, j + 2, 64);
            float a30 = __shfl(p0, j + 3, 64), a31 = __shfl(p1, j + 3, 64);
            float al0 = myhead ? a01 : a00;
            float al1 = myhead ? a11 : a10;
            float al2 = myhead ? a21 : a20;
            float al3 = myhead ? a31 : a30;
            short8 h0v = *(const short8*)(hc + (size_t)sj0 * 512);
            short8 h1v = *(const short8*)(hc + (size_t)sj1 * 512);
            short8 h2v = *(const short8*)(hc + (size_t)sj2 * 512);
            short8 h3v = *(const short8*)(hc + (size_t)sj3 * 512);
#pragma unroll
            for (int q = 0; q < 8; q++) {
                acc[q] += al0 * bf2f((ushort)h0v[q]);
                acc[q] += al1 * bf2f((ushort)h1v[q]);
                acc[q] += al2 * bf2f((ushort)h2v[q]);
                acc[q] += al3 * bf2f((ushort)h3v[q]);
            }
        }
        for (; j < cnt; j++) {
            int s = __shfl(sv, j, 64);
            float a0 = __shfl(p0, j, 64), a1 = __shfl(p1, j, 64);
            float al = myhead ? a1 : a0;
            short8 hv = *(const short8*)(hc + (size_t)s * 512);
#pragma unroll
            for (int q = 0; q < 8; q++) acc[q] += al * bf2f((ushort)hv[q]);
        }
    }

    float v[8];
#pragma unroll
    for (int q = 0; q < 8; q++) v[q] = fmaxf(acc[q] + bias[c + q], 0.f);
    if (outf) {
        float* op = outf + (size_t)n * 512 + c;
        *(floatx4*)op       = (floatx4){v[0], v[1], v[2], v[3]};
        *(floatx4*)(op + 4) = (floatx4){v[4], v[5], v[6], v[7]};
    } else {
        short8 r;
#pragma unroll
        for (int q = 0; q < 8; q++) r[q] = (short)f2bf(v[q]);
        *(short8*)(outb + (size_t)n * 512 + c) = r;
    }
}

// ---------------------------------------------------------------------------
// R11: R8-proven gemm/agg; hist folded into prep (memset before); NEW k_sort
// orders each CSR segment by src for L2 window locality in k_agg.
// ---------------------------------------------------------------------------
extern "C" void kernel_launch(void* const* d_in, const int* in_sizes, int n_in,
                              void* d_out, int out_size, void* d_ws, size_t ws_size,
                              hipStream_t stream) {
    const float* x   = (const float*)d_in[0];
    const int*   adj = (const int*)d_in[1];
    const float* Wfc = (const float*)d_in[2];
    const float* bfc = (const float*)d_in[3];
    const float* W1  = (const float*)d_in[4];
    const float* a1s = (const float*)d_in[5];
    const float* a1d = (const float*)d_in[6];
    const float* b1  = (const float*)d_in[7];
    const float* W2  = (const float*)d_in[8];
    const float* a2s = (const float*)d_in[9];
    const float* a2d = (const float*)d_in[10];
    const float* b2  = (const float*)d_in[11];
    float* out = (float*)d_out;

    char* ws = (char*)d_ws;
    size_t off = 0;
    auto alloc = [&](size_t bytes) -> void* {
        void* p = ws + off;
        off += (bytes + 255) & ~(size_t)255;
        return p;
    };
    ushort* xb   = (ushort*)alloc((size_t)N_NODES * 256 * 2);
    ushort* h0b  = (ushort*)alloc((size_t)N_NODES * 256 * 2);
    ushort* h1b  = (ushort*)alloc((size_t)N_NODES * 512 * 2);
    ushort* g1b  = (ushort*)alloc((size_t)N_NODES * 512 * 2);
    int* counts  = (int*)alloc(N_NODES * 4);
    int* offs    = (int*)alloc((N_NODES + 1) * 4);
    int* cursor  = (int*)alloc(N_NODES * 4);
    int* esrc    = (int*)alloc(E_TOT * 4);
    ushort* WfcT = (ushort*)alloc(256 * 256 * 2);
    ushort* W1T  = (ushort*)alloc(512 * 256 * 2);
    ushort* W2T  = (ushort*)alloc(512 * 512 * 2);
    float* als1  = (float*)alloc(N_NODES * 2 * 4);
    float* ald1  = (float*)alloc(N_NODES * 2 * 4);
    float* als2  = (float*)alloc(N_NODES * 4);
    float* ald2  = (float*)alloc(N_NODES * 4);

    // counts zeroed ahead of the fused prep+hist
    hipMemsetAsync(counts, 0, N_NODES * 4, stream);
    k_prep<<<(PREP_TOT + 255) / 256, 256, 0, stream>>>(x, xb, Wfc, WfcT, W1, W1T,
                                                       W2, W2T, adj, counts);

    // CSR build + per-segment src sort
    k_scan<<<1, 1024, 0, stream>>>(counts, offs, cursor);
    k_scatter<<<(E_TOT + 255) / 256, 256, 0, stream>>>(adj, cursor, esrc);
    k_sort<<<N_NODES / 4, 256, 0, stream>>>(offs, esrc);

    // h0 = relu(x @ Wfc + bfc)            [N,256] bf16
    gemm128<<<dim3(N_NODES / GM, 256 / GN), 256, 0, stream>>>(xb, WfcT, bfc, h0b,
                                                              N_NODES, 256, 256, 1);
    // h1 = h0 @ W1                        [N,512] bf16
    gemm128<<<dim3(N_NODES / GM, 512 / GN), 256, 0, stream>>>(h0b, W1T, nullptr, h1b,
                                                              N_NODES, 512, 256, 0);
    // gat1 attention + aggregation -> relu -> g1b (bf16)
    k_dots<<<N_NODES / 4, 256, 0, stream>>>(h1b, a1s, a1d, als1, ald1, 2);
    k_agg<<<N_NODES / 4, 256, 0, stream>>>(h1b, als1, ald1, offs, esrc, b1,
                                           g1b, nullptr, 2);

    // h2 = g1 @ W2                        [N,512] bf16 (h1b reused; h1 dead)
    gemm128<<<dim3(N_NODES / GM, 512 / GN), 256, 0, stream>>>(g1b, W2T, nullptr, h1b,
                                                              N_NODES, 512, 512, 0);
    // gat2 attention + aggregation -> relu -> out (fp32)
    k_dots<<<N_NODES / 4, 256, 0, stream>>>(h1b, a2s, a2d, als2, ald2, 1);
    k_agg<<<N_NODES / 4, 256, 0, stream>>>(h1b, als2, ald2, offs, esrc, b2,
                                           nullptr, out, 1);
}

// Round 12
// 260.421 us; speedup vs baseline: 1.0536x; 1.0527x over previous
//
#include <hip/hip_runtime.h>

// Problem constants (fixed by the reference)
#define N_NODES 16384
#define N_EDGES 262144
#define E_TOT   (N_EDGES + N_NODES)   // edges + self loops = 278528
#define NEG_SLOPE 0.2f

typedef __attribute__((ext_vector_type(8))) short short8;
typedef __attribute__((ext_vector_type(4))) float floatx4;
typedef __attribute__((ext_vector_type(4))) int intx4;

__device__ __forceinline__ float bf2f(ushort u) {
    return __uint_as_float(((unsigned)u) << 16);
}
__device__ __forceinline__ ushort f2bf(float f) {
    unsigned u = __float_as_uint(f);
    u += 0x7fffu + ((u >> 16) & 1u);   // round-to-nearest-even
    return (ushort)(u >> 16);
}
__device__ __forceinline__ float leaky(float x) {
    return x > 0.f ? x : NEG_SLOPE * x;
}

// ---------------------------------------------------------------------------
// Fused prep: x cast, 3 weight transposes, counts zeroing, als/ald zeroing.
//   [0, 524288)       cast x (8 elems/thread)
//   [+65536)          transpose Wfc 256x256
//   [+131072)         transpose W1  256x512
//   [+262144)         transpose W2  512x512
//   [+4096)           zero counts (int4/thread)
//   [+24576)          zero als1/ald1/als2/ald2 block (98304 floats, int4/thr)
// ---------------------------------------------------------------------------
#define PREP_CAST   524288
#define PREP_T0     (PREP_CAST)
#define PREP_T1     (PREP_T0 + 65536)
#define PREP_T2     (PREP_T1 + 131072)
#define PREP_Z      (PREP_T2 + 262144)
#define PREP_ZA     (PREP_Z + 4096)
#define PREP_TOT    (PREP_ZA + 24576)

__global__ __launch_bounds__(256) void k_prep(const float* __restrict__ x,
                                              ushort* __restrict__ xb,
                                              const float* __restrict__ Wfc,
                                              ushort* __restrict__ WfcT,
                                              const float* __restrict__ W1,
                                              ushort* __restrict__ W1T,
                                              const float* __restrict__ W2,
                                              ushort* __restrict__ W2T,
                                              int* __restrict__ counts,
                                              int* __restrict__ alzero) {
    int idx = blockIdx.x * 256 + threadIdx.x;
    if (idx < PREP_CAST) {
        floatx4 v0 = *(const floatx4*)(x + (size_t)idx * 8);
        floatx4 v1 = *(const floatx4*)(x + (size_t)idx * 8 + 4);
        short8 r;
        r[0] = (short)f2bf(v0[0]); r[1] = (short)f2bf(v0[1]);
        r[2] = (short)f2bf(v0[2]); r[3] = (short)f2bf(v0[3]);
        r[4] = (short)f2bf(v1[0]); r[5] = (short)f2bf(v1[1]);
        r[6] = (short)f2bf(v1[2]); r[7] = (short)f2bf(v1[3]);
        *(short8*)(xb + (size_t)idx * 8) = r;
    } else if (idx < PREP_T1) {
        int t = idx - PREP_T0;                 // K=256, N=256
        int k = t >> 8, n = t & 255;
        WfcT[n * 256 + k] = f2bf(Wfc[t]);
    } else if (idx < PREP_T2) {
        int t = idx - PREP_T1;                 // K=256, N=512
        int k = t >> 9, n = t & 511;
        W1T[n * 256 + k] = f2bf(W1[t]);
    } else if (idx < PREP_Z) {
        int t = idx - PREP_T2;                 // K=512, N=512
        int k = t >> 9, n = t & 511;
        W2T[n * 512 + k] = f2bf(W2[t]);
    } else if (idx < PREP_ZA) {
        int t = idx - PREP_Z;
        *(intx4*)(counts + t * 4) = (intx4){0, 0, 0, 0};
    } else if (idx < PREP_TOT) {
        int t = idx - PREP_ZA;
        *(intx4*)(alzero + t * 4) = (intx4){0, 0, 0, 0};
    }
}

// ---------------------------------------------------------------------------
// CSR build: histogram of dst, shfl-based scan, scatter src indices
// ---------------------------------------------------------------------------
__global__ __launch_bounds__(256) void k_hist(const int* __restrict__ adj,
                                              int* __restrict__ counts) {
    int e = blockIdx.x * 256 + threadIdx.x;
    if (e < E_TOT) {
        int d = (e < N_EDGES) ? adj[N_EDGES + e] : (e - N_EDGES);
        atomicAdd(&counts[d], 1);
    }
}

__global__ __launch_bounds__(1024) void k_scan(const int* __restrict__ counts,
                                               int* __restrict__ offs,
                                               int* __restrict__ cursor) {
    __shared__ int wsum[16];
    int t = threadIdx.x, lane = t & 63, w = t >> 6;
    int local[16];
    int tot = 0;
#pragma unroll
    for (int i = 0; i < 16; i++) {
        local[i] = tot;
        tot += counts[t * 16 + i];
    }
    int incl = tot;   // wave-inclusive scan over thread totals
#pragma unroll
    for (int d = 1; d < 64; d <<= 1) {
        int v = __shfl_up(incl, d, 64);
        if (lane >= d) incl += v;
    }
    if (lane == 63) wsum[w] = incl;
    __syncthreads();
    if (w == 0) {
        int v = (lane < 16) ? wsum[lane] : 0;
#pragma unroll
        for (int d = 1; d < 16; d <<= 1) {
            int u = __shfl_up(v, d, 64);
            if (lane >= d) v += u;
        }
        if (lane < 16) wsum[lane] = v;
    }
    __syncthreads();
    int base = ((w == 0) ? 0 : wsum[w - 1]) + incl - tot;
#pragma unroll
    for (int i = 0; i < 16; i++) {
        int o = base + local[i];
        offs[t * 16 + i] = o;
        cursor[t * 16 + i] = o;
    }
    if (t == 1023) offs[N_NODES] = wsum[15];
}

__global__ __launch_bounds__(256) void k_scatter(const int* __restrict__ adj,
                                                 int* __restrict__ cursor,
                                                 int* __restrict__ esrc) {
    int e = blockIdx.x * 256 + threadIdx.x;
    if (e < E_TOT) {
        int s, d;
        if (e < N_EDGES) { s = adj[e]; d = adj[N_EDGES + e]; }
        else             { s = e - N_EDGES; d = s; }
        int pos = atomicAdd(&cursor[d], 1);
        esrc[pos] = s;
    }
}

// ---------------------------------------------------------------------------
// 128x128-tile GEMM (R8-proven) with OPTIONAL fused attention-logit epilogue.
// BK=64, 4 waves (2x2 of 64x64), 4x4 MFMA tiles/wave. Staging: short8 global
// loads -> ds_write_b128, padded LDS (LDK2=72).
// Fused dots (als != nullptr): lane dots its acc tile against asrc/adst[col]
// (flat col index: head*Cdim + (col % Cdim) == col), 16-lane shfl_xor reduce
// (UNCONDITIONAL — R8 lesson), lane l16==0 atomicAdds per-row partials into
// als/ald (zeroed in k_prep). head = (bn+wn)>>8 is wave-uniform.
// mfma_f32_16x16x32_bf16 layouts (HW-verified):
//   A frag: A[m=lane&15][k=(lane>>4)*8 + j]
//   B frag: B[k=(lane>>4)*8 + j][n=lane&15]  (from BT rows)
//   C/D:    col=lane&15, row=(lane>>4)*4 + reg
// ---------------------------------------------------------------------------
#define GM 128
#define GN 128
#define GK 64
#define LDK2 72

__global__ __launch_bounds__(256) void gemm128(const ushort* __restrict__ A,
                                               const ushort* __restrict__ BT,
                                               const float* __restrict__ bias,
                                               ushort* __restrict__ C,
                                               int M, int Nc, int K, int relu,
                                               const float* __restrict__ asrc,
                                               const float* __restrict__ adst,
                                               float* __restrict__ als,
                                               float* __restrict__ ald,
                                               int heads) {
    __shared__ ushort As[GM * LDK2];   // 18 KB
    __shared__ ushort Bs[GN * LDK2];   // 18 KB
    int tid = threadIdx.x, wave = tid >> 6, lane = tid & 63;
    int quad = lane >> 4, l16 = lane & 15;
    int bm = blockIdx.x * GM, bn = blockIdx.y * GN;
    int wm = (wave & 1) * 64, wn = (wave >> 1) * 64;

    floatx4 acc[4][4];
#pragma unroll
    for (int mi = 0; mi < 4; mi++)
#pragma unroll
        for (int ni = 0; ni < 4; ni++)
            acc[mi][ni] = (floatx4){0.f, 0.f, 0.f, 0.f};

    for (int kb = 0; kb < K; kb += GK) {
        short8 av[4], bv[4];
#pragma unroll
        for (int t = 0; t < 4; t++) {
            int ci = tid + 256 * t;
            int row = ci >> 3, col = (ci & 7) * 8;
            av[t] = *(const short8*)(A + (size_t)(bm + row) * K + kb + col);
            bv[t] = *(const short8*)(BT + (size_t)(bn + row) * K + kb + col);
        }
        __syncthreads();
#pragma unroll
        for (int t = 0; t < 4; t++) {
            int ci = tid + 256 * t;
            int row = ci >> 3, col = (ci & 7) * 8;
            *(short8*)&As[row * LDK2 + col] = av[t];
            *(short8*)&Bs[row * LDK2 + col] = bv[t];
        }
        __syncthreads();

#pragma unroll
        for (int kk = 0; kk < GK; kk += 32) {
            short8 af[4], bf[4];
#pragma unroll
            for (int mi = 0; mi < 4; mi++)
                af[mi] = *(const short8*)&As[(wm + mi * 16 + l16) * LDK2 + kk + quad * 8];
#pragma unroll
            for (int ni = 0; ni < 4; ni++)
                bf[ni] = *(const short8*)&Bs[(wn + ni * 16 + l16) * LDK2 + kk + quad * 8];
#pragma unroll
            for (int mi = 0; mi < 4; mi++)
#pragma unroll
                for (int ni = 0; ni < 4; ni++)
                    acc[mi][ni] = __builtin_amdgcn_mfma_f32_16x16x32_bf16(
                        af[mi], bf[ni], acc[mi][ni], 0, 0, 0);
        }
    }

    // store C
#pragma unroll
    for (int mi = 0; mi < 4; mi++) {
        int row = bm + wm + mi * 16 + quad * 4;
#pragma unroll
        for (int ni = 0; ni < 4; ni++) {
            int col = bn + wn + ni * 16 + l16;
            float bv = bias ? bias[col] : 0.f;
#pragma unroll
            for (int i = 0; i < 4; i++) {
                float v = acc[mi][ni][i] + bv;
                if (relu) v = fmaxf(v, 0.f);
                C[(size_t)(row + i) * Nc + col] = f2bf(v);
            }
        }
    }

    // fused attention logits
    if (als) {
        int head = (bn + wn) >> 8;   // wave-uniform (128-tile aligns w/ 256)
        float aS[4], aD[4];
#pragma unroll
        for (int ni = 0; ni < 4; ni++) {
            int col = bn + wn + ni * 16 + l16;
            aS[ni] = asrc[col];
            aD[ni] = adst[col];
        }
#pragma unroll
        for (int mi = 0; mi < 4; mi++) {
#pragma unroll
            for (int i = 0; i < 4; i++) {
                float dS = 0.f, dD = 0.f;
#pragma unroll
                for (int ni = 0; ni < 4; ni++) {
                    dS += acc[mi][ni][i] * aS[ni];
                    dD += acc[mi][ni][i] * aD[ni];
                }
#pragma unroll
                for (int msk = 1; msk < 16; msk <<= 1) {
                    dS += __shfl_xor(dS, msk, 64);
                    dD += __shfl_xor(dD, msk, 64);
                }
                if (l16 == 0) {
                    int row = bm + wm + mi * 16 + quad * 4 + i;
                    atomicAdd(&als[row * heads + head], dS);
                    atomicAdd(&ald[row * heads + head], dD);
                }
            }
        }
    }
}

// ---------------------------------------------------------------------------
// Segment softmax + aggregation, one wave per node (R8-proven x4 unroll).
// All shfl broadcasts unconditional (R8 lesson).
// ---------------------------------------------------------------------------
__global__ __launch_bounds__(256) void k_agg(const ushort* __restrict__ h,
                                             const float* __restrict__ als,
                                             const float* __restrict__ ald,
                                             const int* __restrict__ offs,
                                             const int* __restrict__ esrc,
                                             const float* __restrict__ bias,
                                             ushort* __restrict__ outb,
                                             float* __restrict__ outf,
                                             int heads) {
    int wave = threadIdx.x >> 6, lane = threadIdx.x & 63;
    int n = blockIdx.x * 4 + wave;
    int base = offs[n];
    int deg  = offs[n + 1] - base;

    int myhead = (heads == 2) ? (lane >> 5) : 0;
    int c = (heads == 2) ? (myhead * 256 + (lane & 31) * 8) : lane * 8;

    float aldh0 = ald[n * heads];
    float aldh1 = (heads == 2) ? ald[n * heads + 1] : 0.f;

    // pass 1: per-head max
    float m0 = -1e30f, m1 = -1e30f;
    for (int cb = 0; cb < deg; cb += 64) {
        int i = cb + lane;
        if (i < deg) {
            int s = esrc[base + i];
            m0 = fmaxf(m0, leaky(als[s * heads] + aldh0));
            if (heads == 2) m1 = fmaxf(m1, leaky(als[s * 2 + 1] + aldh1));
        }
    }
#pragma unroll
    for (int msk = 1; msk < 64; msk <<= 1) {
        m0 = fmaxf(m0, __shfl_xor(m0, msk, 64));
        m1 = fmaxf(m1, __shfl_xor(m1, msk, 64));
    }

    // pass 2: per-head denom
    float s0 = 0.f, s1 = 0.f;
    for (int cb = 0; cb < deg; cb += 64) {
        int i = cb + lane;
        if (i < deg) {
            int s = esrc[base + i];
            s0 += __expf(leaky(als[s * heads] + aldh0) - m0);
            if (heads == 2) s1 += __expf(leaky(als[s * 2 + 1] + aldh1) - m1);
        }
    }
#pragma unroll
    for (int msk = 1; msk < 64; msk <<= 1) {
        s0 += __shfl_xor(s0, msk, 64);
        s1 += __shfl_xor(s1, msk, 64);
    }
    float inv0 = 1.f / (s0 + 1e-16f);
    float inv1 = 1.f / (s1 + 1e-16f);

    // pass 3: weighted gather-accumulate, 8 channels (16B) per lane per edge
    float acc[8];
#pragma unroll
    for (int q = 0; q < 8; q++) acc[q] = 0.f;
    const ushort* hc = h + c;

    for (int cb = 0; cb < deg; cb += 64) {
        int i = cb + lane;
        int sv = 0;
        float p0 = 0.f, p1 = 0.f;
        if (i < deg) {
            sv = esrc[base + i];
            p0 = __expf(leaky(als[sv * heads] + aldh0) - m0) * inv0;
            if (heads == 2) p1 = __expf(leaky(als[sv * 2 + 1] + aldh1) - m1) * inv1;
        }
        int cnt = min(64, deg - cb);
        int j = 0;
        for (; j + 4 <= cnt; j += 4) {
            int sj0 = __shfl(sv, j, 64);
            int sj1 = __shfl(sv, j + 1, 64);
            int sj2 = __shfl(sv, j + 2, 64);
            int sj3 = __shfl(sv, j + 3, 64);
            float a00 = __shfl(p0, j, 64),     a01 = __shfl(p1, j, 64);
            float a10 = __shfl(p0, j + 1, 64), a11 = __shfl(p1, j + 1, 64);
            float a20 = __shfl(p0, j + 2, 64), a21 = __shfl(p1, j + 2, 64);
            float a30 = __shfl(p0, j + 3, 64), a31 = __shfl(p1, j + 3, 64);
            float al0 = myhead ? a01 : a00;
            float al1 = myhead ? a11 : a10;
            float al2 = myhead ? a21 : a20;
            float al3 = myhead ? a31 : a30;
            short8 h0v = *(const short8*)(hc + (size_t)sj0 * 512);
            short8 h1v = *(const short8*)(hc + (size_t)sj1 * 512);
            short8 h2v = *(const short8*)(hc + (size_t)sj2 * 512);
            short8 h3v = *(const short8*)(hc + (size_t)sj3 * 512);
#pragma unroll
            for (int q = 0; q < 8; q++) {
                acc[q] += al0 * bf2f((ushort)h0v[q]);
                acc[q] += al1 * bf2f((ushort)h1v[q]);
                acc[q] += al2 * bf2f((ushort)h2v[q]);
                acc[q] += al3 * bf2f((ushort)h3v[q]);
            }
        }
        for (; j < cnt; j++) {
            int s = __shfl(sv, j, 64);
            float a0 = __shfl(p0, j, 64), a1 = __shfl(p1, j, 64);
            float al = myhead ? a1 : a0;
            short8 hv = *(const short8*)(hc + (size_t)s * 512);
#pragma unroll
            for (int q = 0; q < 8; q++) acc[q] += al * bf2f((ushort)hv[q]);
        }
    }

    float v[8];
#pragma unroll
    for (int q = 0; q < 8; q++) v[q] = fmaxf(acc[q] + bias[c + q], 0.f);
    if (outf) {
        float* op = outf + (size_t)n * 512 + c;
        *(floatx4*)op       = (floatx4){v[0], v[1], v[2], v[3]};
        *(floatx4*)(op + 4) = (floatx4){v[4], v[5], v[6], v[7]};
    } else {
        short8 r;
#pragma unroll
        for (int q = 0; q < 8; q++) r[q] = (short)f2bf(v[q]);
        *(short8*)(outb + (size_t)n * 512 + c) = r;
    }
}

// ---------------------------------------------------------------------------
// R12: R8 base; k_dots fused into gemm128 epilogue (atomic fp32 partial dots,
// als/ald zeroed in k_prep); sort/memset dropped. 9 dispatches.
// ---------------------------------------------------------------------------
extern "C" void kernel_launch(void* const* d_in, const int* in_sizes, int n_in,
                              void* d_out, int out_size, void* d_ws, size_t ws_size,
                              hipStream_t stream) {
    const float* x   = (const float*)d_in[0];
    const int*   adj = (const int*)d_in[1];
    const float* Wfc = (const float*)d_in[2];
    const float* bfc = (const float*)d_in[3];
    const float* W1  = (const float*)d_in[4];
    const float* a1s = (const float*)d_in[5];
    const float* a1d = (const float*)d_in[6];
    const float* b1  = (const float*)d_in[7];
    const float* W2  = (const float*)d_in[8];
    const float* a2s = (const float*)d_in[9];
    const float* a2d = (const float*)d_in[10];
    const float* b2  = (const float*)d_in[11];
    float* out = (float*)d_out;

    char* ws = (char*)d_ws;
    size_t off = 0;
    auto alloc = [&](size_t bytes) -> void* {
        void* p = ws + off;
        off += (bytes + 255) & ~(size_t)255;
        return p;
    };
    ushort* xb   = (ushort*)alloc((size_t)N_NODES * 256 * 2);
    ushort* h0b  = (ushort*)alloc((size_t)N_NODES * 256 * 2);
    ushort* h1b  = (ushort*)alloc((size_t)N_NODES * 512 * 2);
    ushort* g1b  = (ushort*)alloc((size_t)N_NODES * 512 * 2);
    int* counts  = (int*)alloc(N_NODES * 4);
    int* offs    = (int*)alloc((N_NODES + 1) * 4);
    int* cursor  = (int*)alloc(N_NODES * 4);
    int* esrc    = (int*)alloc(E_TOT * 4);
    ushort* WfcT = (ushort*)alloc(256 * 256 * 2);
    ushort* W1T  = (ushort*)alloc(512 * 256 * 2);
    ushort* W2T  = (ushort*)alloc(512 * 512 * 2);
    // als/ald block: contiguous (sizes are 256B multiples -> no alloc gaps),
    // zeroed as one segment in k_prep (98304 floats total).
    float* als1  = (float*)alloc(N_NODES * 2 * 4);   // 32768 f
    float* ald1  = (float*)alloc(N_NODES * 2 * 4);   // 32768 f
    float* als2  = (float*)alloc(N_NODES * 4);       // 16384 f
    float* ald2  = (float*)alloc(N_NODES * 4);       // 16384 f

    // fused prep: cast x, transpose weights, zero counts + als/ald block
    k_prep<<<PREP_TOT / 256, 256, 0, stream>>>(x, xb, Wfc, WfcT, W1, W1T, W2, W2T,
                                               counts, (int*)als1);

    // CSR build
    k_hist<<<(E_TOT + 255) / 256, 256, 0, stream>>>(adj, counts);
    k_scan<<<1, 1024, 0, stream>>>(counts, offs, cursor);
    k_scatter<<<(E_TOT + 255) / 256, 256, 0, stream>>>(adj, cursor, esrc);

    // h0 = relu(x @ Wfc + bfc)            [N,256] bf16 (no dots)
    gemm128<<<dim3(N_NODES / GM, 256 / GN), 256, 0, stream>>>(
        xb, WfcT, bfc, h0b, N_NODES, 256, 256, 1,
        nullptr, nullptr, nullptr, nullptr, 0);
    // h1 = h0 @ W1                        [N,512] bf16  + fused gat1 logits
    gemm128<<<dim3(N_NODES / GM, 512 / GN), 256, 0, stream>>>(
        h0b, W1T, nullptr, h1b, N_NODES, 512, 256, 0,
        a1s, a1d, als1, ald1, 2);
    // gat1 aggregation -> relu -> g1b (bf16)
    k_agg<<<N_NODES / 4, 256, 0, stream>>>(h1b, als1, ald1, offs, esrc, b1,
                                           g1b, nullptr, 2);

    // h2 = g1 @ W2                        [N,512] bf16  + fused gat2 logits
    gemm128<<<dim3(N_NODES / GM, 512 / GN), 256, 0, stream>>>(
        g1b, W2T, nullptr, h1b, N_NODES, 512, 512, 0,
        a2s, a2d, als2, ald2, 1);
    // gat2 aggregation -> relu -> out (fp32)
    k_agg<<<N_NODES / 4, 256, 0, stream>>>(h1b, als2, ald2, offs, esrc, b2,
                                           nullptr, out, 1);
}